// Round 7
// baseline (779.357 us; speedup 1.0000x reference)
//
#include <hip/hip_runtime.h>
#include <hip/hip_bf16.h>

typedef unsigned short u16;
typedef unsigned int u32;
typedef __attribute__((ext_vector_type(8))) short short8;
typedef __attribute__((ext_vector_type(4))) float f4;
typedef __attribute__((ext_vector_type(4))) u32 u4;
typedef __attribute__((ext_vector_type(4))) _Float16 h4;

#define MFMA(a, b, c) __builtin_amdgcn_mfma_f32_16x16x32_bf16((a), (b), (c), 0, 0, 0)

// ---- constants ----
#define TT 256
#define BB 1024
#define LPH 32                 // timesteps per phase
#define NPH 8                  // phases (8 x 32 = 256)
#define ROWS_PH (LPH * BB)     // 32768 rows per phase
#define L2E 1.442695040888963f

// ws layout in u16 units (total (16777216+160768+131072+262144)*2 = 34,662,400 B,
// well under the 67.4 MB the previous session's layout established as available):
#define WS_GX   0                      // 16,777,216 u16: per-phase gate preacts fp16
#define GX_SZ   (ROWS_PH * 512)        // [bI][t_local][col(512)][row(16)] fp16
#define WS_WF   GX_SZ
#define OFF_W1  0
#define OFF_W2  16384
#define OFF_W3  20480
#define OFF_WIH 24576
#define OFF_WHH 90112
#define OFF_WA  155648
#define OFF_BGX 159744                 // 512 f32 combined scaled gate biases
#define WF_TOT  160768
#define WS_STH  (WS_WF + WF_TOT)       // 131072 u16: h state bf16 [B][H]
#define WS_STC  (WS_STH + 131072)      // 131072 f32: c state     [B][H]

static __device__ __forceinline__ u16 f2bf(float f) {
    u32 u = __float_as_uint(f);
    u32 r = (u + 0x7FFFu + ((u >> 16) & 1u)) >> 16;
    return (u16)r;
}
static __device__ __forceinline__ short8 pack8(f4 a, f4 b) {
    short8 r;
    r[0] = (short)f2bf(a[0]); r[1] = (short)f2bf(a[1]);
    r[2] = (short)f2bf(a[2]); r[3] = (short)f2bf(a[3]);
    r[4] = (short)f2bf(b[0]); r[5] = (short)f2bf(b[1]);
    r[6] = (short)f2bf(b[2]); r[7] = (short)f2bf(b[3]);
    return r;
}
// pre-scaled logistic: expects x already multiplied by log2(e) (folded into W/b)
static __device__ __forceinline__ float sig_pre(float x) {
    return __builtin_amdgcn_rcpf(1.f + __builtin_amdgcn_exp2f(-x));
}
static __device__ __forceinline__ float tanhf_fast(float x) {
    return 2.f * __builtin_amdgcn_rcpf(1.f + __builtin_amdgcn_exp2f(-2.885390081777927f * x)) - 1.f;
}

// ---------------- K0: convert weights fp32 -> bf16 fragment order ----------------
static __device__ void convW128(const float* src, int Nn, u16* dst, int tid, int nth) {
    int tot = Nn * 128;
    for (int d = tid; d < tot; d += nth) {
        int j = d & 7, l = (d >> 3) & 63, ck = d >> 9;
        int kc = ck & 3, nt = ck >> 2;
        int n = nt * 16 + (l & 15), k = kc * 32 + ((l >> 4) << 3) + j;
        dst[d] = f2bf(src[n * 128 + k]);
    }
}
// gate-weight variant: rows scaled by log2e (gates i,f,o) or 2*log2e (gate g)
static __device__ void convW128g(const float* src, u16* dst, int tid, int nth) {
    int tot = 512 * 128;
    for (int d = tid; d < tot; d += nth) {
        int j = d & 7, l = (d >> 3) & 63, ck = d >> 9;
        int kc = ck & 3, nt = ck >> 2;
        int n = nt * 16 + (l & 15), k = kc * 32 + ((l >> 4) << 3) + j;
        float sc = ((n >> 7) == 2) ? (2.f * L2E) : L2E;
        dst[d] = f2bf(src[n * 128 + k] * sc);
    }
}
static __device__ void convW32(const float* src, int Nn, u16* dst, int tid, int nth) {
    int tot = Nn * 32;
    for (int d = tid; d < tot; d += nth) {
        int j = d & 7, l = (d >> 3) & 63, nt = d >> 9;
        int n = nt * 16 + (l & 15), k = ((l >> 4) << 3) + j;
        dst[d] = f2bf(src[n * 32 + k]);
    }
}

__global__ void k0_conv(const float* __restrict__ W1, const float* __restrict__ W2,
                        const float* __restrict__ W3, const float* __restrict__ Wih,
                        const float* __restrict__ Whh, const float* __restrict__ Wa,
                        const float* __restrict__ Wc, const float* __restrict__ bih,
                        const float* __restrict__ bhh, u16* __restrict__ wf) {
    int tid = blockIdx.x * blockDim.x + threadIdx.x;
    int nth = gridDim.x * blockDim.x;
    convW128(W1, 128, wf + OFF_W1, tid, nth);
    convW128(W2, 32, wf + OFF_W2, tid, nth);
    convW32(W3, 128, wf + OFF_W3, tid, nth);
    convW128g(Wih, wf + OFF_WIH, tid, nth);
    convW128g(Whh, wf + OFF_WHH, tid, nth);
    // WaWc: padded 32 x 128: rows 0..17 = Wa, 18 = Wc, 19..31 = 0
    for (int d = tid; d < 32 * 128; d += nth) {
        int j = d & 7, l = (d >> 3) & 63, ck = d >> 9;
        int kc = ck & 3, nt = ck >> 2;
        int n = nt * 16 + (l & 15), k = kc * 32 + ((l >> 4) << 3) + j;
        float v = (n < 18) ? Wa[n * 128 + k] : ((n == 18) ? Wc[k] : 0.f);
        wf[OFF_WA + d] = f2bf(v);
    }
    // combined scaled gate biases: bgx[col] = (bih+bhh)*sc
    float* bgxf = (float*)(wf + OFF_BGX);
    for (int d = tid; d < 512; d += nth) {
        float sc = ((d >> 7) == 2) ? (2.f * L2E) : L2E;
        bgxf[d] = (bih[d] + bhh[d]) * sc;
    }
}

// ---------------- K1: encoder (3 layers) + gate-preact GEMM, one phase ----------------
// 512 blocks x 256 thr; 2048 waves = 2048 chunks = 32 t_local x 64 bI.
// Writes gx[(bI*32+tl)*8192 + col*16 + row] fp16 = hid3 @ Wih^T + bias (pre-scaled).
__global__ __launch_bounds__(256, 2) void k1_enc(
    const float* __restrict__ x, const float* __restrict__ b1, const float* __restrict__ b2,
    const float* __restrict__ b3, const u16* __restrict__ wf, u16* __restrict__ gx, int t0) {
    __shared__ __align__(16) u16 scr[4][2560];  // per-wave: 2048 (K=128 frag) + 512 (K=32 frag)

    int tid = threadIdx.x, wv = tid >> 6, lane = tid & 63;
    int m = lane & 15, q = lane >> 4;
    u16* s1 = scr[wv];
    u16* s2 = scr[wv] + 2048;
    const short8* W1v = (const short8*)(wf + OFF_W1);
    const short8* W2v = (const short8*)(wf + OFF_W2);
    const short8* W3v = (const short8*)(wf + OFF_W3);
    const short8* WIv = (const short8*)(wf + OFF_WIH);
    const float* bgxf = (const float*)(wf + OFF_BGX);

    int wid = blockIdx.x * 4 + wv;   // 0..2047
    int bI = wid & 63, tl = wid >> 6;

    // ---- encoder layers (as verified in rounds 2-6) ----
    short8 a1[4];
    const float* xr = x + ((size_t)(t0 + tl) * BB + bI * 16 + m) * 128 + q * 8;
#pragma unroll
    for (int kc = 0; kc < 4; ++kc) {
        f4 f0 = *(const f4*)(xr + kc * 32);
        f4 f1 = *(const f4*)(xr + kc * 32 + 4);
        a1[kc] = pack8(f0, f1);
    }
    // Layer 1: 128 -> 128
#pragma unroll
    for (int nt = 0; nt < 8; ++nt) {
        f4 acc = {0.f, 0.f, 0.f, 0.f};
#pragma unroll
        for (int kc = 0; kc < 4; ++kc) acc = MFMA(a1[kc], W1v[(nt * 4 + kc) * 64 + lane], acc);
        int col = nt * 16 + m;
        float bb = b1[col];
        int base = (col >> 5) * 512 + ((col >> 3) & 3) * 128 + (col & 7);
#pragma unroll
        for (int p = 0; p < 4; ++p) {
            float v = acc[p] + bb; v = v > 0.f ? v : 0.f;
            s1[base + (q * 4 + p) * 8] = f2bf(v);
        }
    }
    asm volatile("s_waitcnt lgkmcnt(0)" ::: "memory");  // scratch is wave-private
    short8 a2[4];
#pragma unroll
    for (int kc = 0; kc < 4; ++kc) a2[kc] = *(const short8*)(s1 + kc * 512 + lane * 8);
    // Layer 2: 128 -> 32
#pragma unroll
    for (int nt = 0; nt < 2; ++nt) {
        f4 acc = {0.f, 0.f, 0.f, 0.f};
#pragma unroll
        for (int kc = 0; kc < 4; ++kc) acc = MFMA(a2[kc], W2v[(nt * 4 + kc) * 64 + lane], acc);
        int col = nt * 16 + m;
        float bb = b2[col];
        int base = (col >> 3) * 128 + (col & 7);
#pragma unroll
        for (int p = 0; p < 4; ++p) {
            float v = acc[p] + bb; v = v > 0.f ? v : 0.f;
            s2[base + (q * 4 + p) * 8] = f2bf(v);
        }
    }
    asm volatile("s_waitcnt lgkmcnt(0)" ::: "memory");
    short8 a3 = *(const short8*)(s2 + lane * 8);
    // Layer 3: 32 -> 128
#pragma unroll
    for (int nt = 0; nt < 8; ++nt) {
        f4 acc = {0.f, 0.f, 0.f, 0.f};
        acc = MFMA(a3, W3v[nt * 64 + lane], acc);
        int col = nt * 16 + m;
        float bb = b3[col];
        int base = (col >> 5) * 512 + ((col >> 3) & 3) * 128 + (col & 7);
#pragma unroll
        for (int p = 0; p < 4; ++p) {
            float v = acc[p] + bb; v = v > 0.f ? v : 0.f;
            s1[base + (q * 4 + p) * 8] = f2bf(v);
        }
    }
    asm volatile("s_waitcnt lgkmcnt(0)" ::: "memory");
    // ---- gate-preact GEMM: gx = hid3 @ Wih^T + (bih+bhh), all pre-scaled ----
    short8 a4[4];
#pragma unroll
    for (int kc = 0; kc < 4; ++kc) a4[kc] = *(const short8*)(s1 + kc * 512 + lane * 8);
    _Float16* gxo = (_Float16*)gx + (size_t)(bI * LPH + tl) * 8192;
#pragma unroll 4
    for (int nt = 0; nt < 32; ++nt) {
        f4 acc = {0.f, 0.f, 0.f, 0.f};
#pragma unroll
        for (int kc = 0; kc < 4; ++kc) acc = MFMA(a4[kc], WIv[(nt * 4 + kc) * 64 + lane], acc);
        int col = nt * 16 + m;
        float bb = bgxf[col];
        h4 hv;
#pragma unroll
        for (int p = 0; p < 4; ++p) hv[p] = (_Float16)(acc[p] + bb);
        *(h4*)(gxo + col * 16 + 4 * q) = hv;  // [col][row] fp16, 8B store
    }
}

// ---------------- K3: LSTM scan phase + fused heads (64 blocks x 512 thr) ----------------
// Whh fragments staged in LDS (128 KB) -- ends the round-2..6 register-allocator fight:
// per step each wave does 16 conflict-free ds_read_b128 instead of 128KB/CU L2 reloads.
// The x-path MFMAs are gone entirely (precomputed gate preacts streamed from gx).
__global__ __launch_bounds__(512, 1) void k3_scan(
    const u16* __restrict__ gx, const u16* __restrict__ wf, const float* __restrict__ done,
    const float* __restrict__ h0, const float* __restrict__ c0,
    u16* __restrict__ sth, float* __restrict__ stc,
    const float* __restrict__ ba, const float* __restrict__ bc,
    float* __restrict__ out, int t0) {
    __shared__ __align__(16) u16 whl[65536];     // 128 KB: Whh fragments, linear
    __shared__ __align__(16) u16 hbuf[2][2048];  // 16 rows x 128 bf16, frag order, dbl-buffered

    int tid = threadIdx.x, wv = tid >> 6, lane = tid & 63;
    int m = lane & 15, q = lane >> 4;
    int bI = blockIdx.x, rb = bI * 16;
    int u = wv * 16 + m;  // this wave's hidden-unit column

    // stage Whh frags global -> LDS (one-time, 16 u4 copies/thread)
    {
        const u4* src = (const u4*)(wf + OFF_WHH);
        u4* dst = (u4*)whl;
        for (int i = tid; i < 8192; i += 512) dst[i] = src[i];
    }
    // head fragments (waves 0,1): tiny, L1-hot if remat'd
    const short8* WAv = (const short8*)(wf + OFF_WA);
    short8 wab[4];
    float hb = 0.f;
    int hcol = wv * 16 + m;
    if (wv < 2) {
#pragma unroll
        for (int kc = 0; kc < 4; ++kc) wab[kc] = WAv[(wv * 4 + kc) * 64 + lane];
        if (hcol < 18) hb = ba[hcol];
        else if (hcol == 18) hb = bc[0];
    }
    // init state: phase 0 from h0/c0 inputs, later phases from carried state
    float cst[4];
#pragma unroll
    for (int k = 0; k < 4; ++k) {
        int r = 4 * q + k;
        int hidx = (u >> 5) * 512 + (((u >> 3) & 3) * 16 + r) * 8 + (u & 7);
        if (t0 == 0) {
            cst[k] = c0[(size_t)(rb + r) * 128 + u];
            hbuf[0][hidx] = f2bf(h0[(size_t)(rb + r) * 128 + u]);
        } else {
            cst[k] = stc[(size_t)(rb + r) * 128 + u];
            hbuf[0][hidx] = sth[(size_t)(rb + r) * 128 + u];
        }
    }
    const _Float16* gxf = (const _Float16*)gx + (size_t)bI * (LPH * 8192);
    // 2-deep prefetch: gA/dA = even local steps, gB/dB = odd
    h4 gA[4], gB[4];
    f4 dA, dB;
#pragma unroll
    for (int g = 0; g < 4; ++g) {
        gA[g] = *(const h4*)(gxf + (g * 128 + u) * 16 + 4 * q);
        gB[g] = *(const h4*)(gxf + 8192 + (g * 128 + u) * 16 + 4 * q);
    }
    dA = *(const f4*)(done + (size_t)t0 * BB + rb + 4 * q);
    dB = *(const f4*)(done + (size_t)(t0 + 1) * BB + rb + 4 * q);
    __syncthreads();

    // step s: consume GU/DU, refill them for s+2 (round-4-verified single-buffer pattern)
    auto step = [&](int s, h4 (&GU)[4], f4& DU) __attribute__((always_inline)) {
        const u16* hc = hbuf[s & 1];
        u16* hn = hbuf[(s + 1) & 1];
        short8 ah[4];
#pragma unroll
        for (int kc = 0; kc < 4; ++kc) ah[kc] = *(const short8*)(hc + kc * 512 + lane * 8);
        f4 aH[4];
#pragma unroll
        for (int g = 0; g < 4; ++g) aH[g] = (f4){0.f, 0.f, 0.f, 0.f};
#pragma unroll
        for (int kc = 0; kc < 4; ++kc)
#pragma unroll
            for (int g = 0; g < 4; ++g) {
                short8 whf = *(const short8*)(whl + ((g * 8 + wv) * 4 + kc) * 512 + lane * 8);
                aH[g] = MFMA(ah[kc], whf, aH[g]);
            }
        // fused head for global step t-1 (ah holds h_{t-1}); waves 0,1 only
        if (wv < 2 && (t0 + s) > 0) {
            f4 hacc = {0.f, 0.f, 0.f, 0.f};
#pragma unroll
            for (int kc = 0; kc < 4; ++kc) hacc = MFMA(ah[kc], wab[kc], hacc);
            if (hcol < 19) {
                size_t n0 = (size_t)(t0 + s - 1) * BB + rb + 4 * q;
#pragma unroll
                for (int p = 0; p < 4; ++p) out[(n0 + p) * 19 + hcol] = hacc[p] + hb;
            }
        }
        // combine preacts; then GU/DU are dead and can be refilled early
        f4 mmv, pre[4];
#pragma unroll
        for (int k = 0; k < 4; ++k) mmv[k] = 1.f - DU[k];
#pragma unroll
        for (int g = 0; g < 4; ++g)
#pragma unroll
            for (int k = 0; k < 4; ++k) pre[g][k] = (float)GU[g][k] + mmv[k] * aH[g][k];
        if (s + 2 < LPH) {
#pragma unroll
            for (int g = 0; g < 4; ++g)
                GU[g] = *(const h4*)(gxf + (size_t)(s + 2) * 8192 + (g * 128 + u) * 16 + 4 * q);
            DU = *(const f4*)(done + (size_t)(t0 + s + 2) * BB + rb + 4 * q);
        }
#pragma unroll
        for (int k = 0; k < 4; ++k) {
            float ii = sig_pre(pre[0][k]), ff = sig_pre(pre[1][k]), oo = sig_pre(pre[3][k]);
            float gg = 2.f * sig_pre(pre[2][k]) - 1.f;   // tanh via pre-scaled sigmoid
            float cc = ff * (mmv[k] * cst[k]) + ii * gg;
            cst[k] = cc;
            float hh = oo * tanhf_fast(cc);
            u16 hbits = f2bf(hh);
            hn[(u >> 5) * 512 + (((u >> 3) & 3) * 16 + (4 * q + k)) * 8 + (u & 7)] = hbits;
            if (s == LPH - 1) {   // carry state to next phase
                sth[(size_t)(rb + 4 * q + k) * 128 + u] = hbits;
                stc[(size_t)(rb + 4 * q + k) * 128 + u] = cc;
            }
        }
        // barrier needs ONLY the LDS writes drained; gx/done prefetch + out stores in flight
        asm volatile("s_waitcnt lgkmcnt(0)" ::: "memory");
        __builtin_amdgcn_s_barrier();
        asm volatile("" ::: "memory");
    };

    for (int s = 0; s < LPH; s += 2) {
        step(s, gA, dA);
        step(s + 1, gB, dB);
    }
    // final head (t_out = 255) only in the last phase; h_255 lives in hbuf[0]
    if (t0 + LPH == TT && wv < 2) {
        short8 ah[4];
#pragma unroll
        for (int kc = 0; kc < 4; ++kc) ah[kc] = *(const short8*)(hbuf[0] + kc * 512 + lane * 8);
        f4 hacc = {0.f, 0.f, 0.f, 0.f};
#pragma unroll
        for (int kc = 0; kc < 4; ++kc) hacc = MFMA(ah[kc], wab[kc], hacc);
        if (hcol < 19) {
            size_t n0 = (size_t)(TT - 1) * BB + rb + 4 * q;
#pragma unroll
            for (int p = 0; p < 4; ++p) out[(n0 + p) * 19 + hcol] = hacc[p] + hb;
        }
    }
}

extern "C" void kernel_launch(void* const* d_in, const int* in_sizes, int n_in,
                              void* d_out, int out_size, void* d_ws, size_t ws_size,
                              hipStream_t stream) {
    const float* x    = (const float*)d_in[0];
    const float* done = (const float*)d_in[1];
    const float* h0   = (const float*)d_in[2];
    const float* c0   = (const float*)d_in[3];
    const float* W1   = (const float*)d_in[4];
    const float* b1   = (const float*)d_in[5];
    const float* W2   = (const float*)d_in[6];
    const float* b2   = (const float*)d_in[7];
    const float* W3   = (const float*)d_in[8];
    const float* b3   = (const float*)d_in[9];
    const float* Wih  = (const float*)d_in[10];
    const float* Whh  = (const float*)d_in[11];
    const float* bih  = (const float*)d_in[12];
    const float* bhh  = (const float*)d_in[13];
    const float* Wa   = (const float*)d_in[14];
    const float* ba   = (const float*)d_in[15];
    const float* Wc   = (const float*)d_in[16];
    const float* bc   = (const float*)d_in[17];
    float* out = (float*)d_out;

    u16* ws   = (u16*)d_ws;
    u16* gxb  = ws + WS_GX;                 // 32 MB rotating fp16 gate-preact buffer
    u16* wf   = ws + WS_WF;                 // 321 KB converted weights + biases
    u16* sth  = ws + WS_STH;                // 256 KB h state (bf16)
    float* stc = (float*)(ws + WS_STC);     // 512 KB c state (f32)
    // total ws needed: 34,662,400 bytes (half of the previous 67.4 MB layout)

    hipLaunchKernelGGL(k0_conv, dim3(128), dim3(256), 0, stream,
                       W1, W2, W3, Wih, Whh, Wa, Wc, bih, bhh, wf);
    for (int ph = 0; ph < NPH; ++ph) {
        int t0 = ph * LPH;
        hipLaunchKernelGGL(k1_enc, dim3(512), dim3(256), 0, stream,
                           x, b1, b2, b3, wf, gxb, t0);
        hipLaunchKernelGGL(k3_scan, dim3(64), dim3(512), 0, stream,
                           gxb, wf, done, h0, c0, sth, stc, ba, bc, out, t0);
    }
}

// Round 8
// 727.567 us; speedup vs baseline: 1.0712x; 1.0712x over previous
//
#include <hip/hip_runtime.h>
#include <hip/hip_bf16.h>

typedef unsigned short u16;
typedef unsigned int u32;
typedef __attribute__((ext_vector_type(8))) short short8;
typedef __attribute__((ext_vector_type(4))) float f4;
typedef __attribute__((ext_vector_type(4))) u32 u4;
typedef __attribute__((ext_vector_type(4))) _Float16 h4;

#define MFMA(a, b, c) __builtin_amdgcn_mfma_f32_16x16x32_bf16((a), (b), (c), 0, 0, 0)

// ---- constants ----
#define TT 256
#define BB 1024
#define NN (TT * BB)           // 262144 rows
#define L2E 1.442695040888963f

// ws layout in u16 units. Round-7's rocprof showed the harness memsets 512 MiB of
// workspace per iteration => ws_size ~= 536,870,912 B. Full gx (268.4 MB) fits.
#define WS_GX   0                          // 134,217,728 u16: fp16 gate preacts
                                           //   [(bI*256 + t)*8192 + col*16 + row]
#define WS_WF   134217728
#define OFF_W1  0
#define OFF_W2  16384
#define OFF_W3  20480
#define OFF_WIH 24576
#define OFF_WHH 90112
#define OFF_WA  155648
#define OFF_BGX 159744                     // 512 f32 combined scaled gate biases
#define WF_TOT  160768
// total ws: (134217728 + 160768) * 2 = 268,756,992 B

// ONE-TIME opacity pin: value becomes INLINEASM-defined => never rematerializable.
// Round 5 proved this forces allocation (VGPR jumped to the 256 cap); it lost only
// because demand (430) > cap. Scan demand is now ~165 < 256 => weights stay resident.
#define OPAQ(x) asm volatile("" : "+v"(x))

static __device__ __forceinline__ u16 f2bf(float f) {
    u32 u = __float_as_uint(f);
    u32 r = (u + 0x7FFFu + ((u >> 16) & 1u)) >> 16;
    return (u16)r;
}
static __device__ __forceinline__ short8 pack8(f4 a, f4 b) {
    short8 r;
    r[0] = (short)f2bf(a[0]); r[1] = (short)f2bf(a[1]);
    r[2] = (short)f2bf(a[2]); r[3] = (short)f2bf(a[3]);
    r[4] = (short)f2bf(b[0]); r[5] = (short)f2bf(b[1]);
    r[6] = (short)f2bf(b[2]); r[7] = (short)f2bf(b[3]);
    return r;
}
// pre-scaled logistic: expects x already multiplied by log2(e) (folded into W/b)
static __device__ __forceinline__ float sig_pre(float x) {
    return __builtin_amdgcn_rcpf(1.f + __builtin_amdgcn_exp2f(-x));
}
static __device__ __forceinline__ float tanhf_fast(float x) {
    return 2.f * __builtin_amdgcn_rcpf(1.f + __builtin_amdgcn_exp2f(-2.885390081777927f * x)) - 1.f;
}

// ---------------- K0: convert weights fp32 -> bf16 fragment order ----------------
static __device__ void convW128(const float* src, int Nn, u16* dst, int tid, int nth) {
    int tot = Nn * 128;
    for (int d = tid; d < tot; d += nth) {
        int j = d & 7, l = (d >> 3) & 63, ck = d >> 9;
        int kc = ck & 3, nt = ck >> 2;
        int n = nt * 16 + (l & 15), k = kc * 32 + ((l >> 4) << 3) + j;
        dst[d] = f2bf(src[n * 128 + k]);
    }
}
// gate-weight variant: rows scaled by log2e (gates i,f,o) or 2*log2e (gate g)
static __device__ void convW128g(const float* src, u16* dst, int tid, int nth) {
    int tot = 512 * 128;
    for (int d = tid; d < tot; d += nth) {
        int j = d & 7, l = (d >> 3) & 63, ck = d >> 9;
        int kc = ck & 3, nt = ck >> 2;
        int n = nt * 16 + (l & 15), k = kc * 32 + ((l >> 4) << 3) + j;
        float sc = ((n >> 7) == 2) ? (2.f * L2E) : L2E;
        dst[d] = f2bf(src[n * 128 + k] * sc);
    }
}
static __device__ void convW32(const float* src, int Nn, u16* dst, int tid, int nth) {
    int tot = Nn * 32;
    for (int d = tid; d < tot; d += nth) {
        int j = d & 7, l = (d >> 3) & 63, nt = d >> 9;
        int n = nt * 16 + (l & 15), k = ((l >> 4) << 3) + j;
        dst[d] = f2bf(src[n * 32 + k]);
    }
}

__global__ void k0_conv(const float* __restrict__ W1, const float* __restrict__ W2,
                        const float* __restrict__ W3, const float* __restrict__ Wih,
                        const float* __restrict__ Whh, const float* __restrict__ Wa,
                        const float* __restrict__ Wc, const float* __restrict__ bih,
                        const float* __restrict__ bhh, u16* __restrict__ wf) {
    int tid = blockIdx.x * blockDim.x + threadIdx.x;
    int nth = gridDim.x * blockDim.x;
    convW128(W1, 128, wf + OFF_W1, tid, nth);
    convW128(W2, 32, wf + OFF_W2, tid, nth);
    convW32(W3, 128, wf + OFF_W3, tid, nth);
    convW128g(Wih, wf + OFF_WIH, tid, nth);
    convW128g(Whh, wf + OFF_WHH, tid, nth);
    // WaWc: padded 32 x 128: rows 0..17 = Wa, 18 = Wc, 19..31 = 0
    for (int d = tid; d < 32 * 128; d += nth) {
        int j = d & 7, l = (d >> 3) & 63, ck = d >> 9;
        int kc = ck & 3, nt = ck >> 2;
        int n = nt * 16 + (l & 15), k = kc * 32 + ((l >> 4) << 3) + j;
        float v = (n < 18) ? Wa[n * 128 + k] : ((n == 18) ? Wc[k] : 0.f);
        wf[OFF_WA + d] = f2bf(v);
    }
    // combined scaled gate biases: bgx[col] = (bih+bhh)*sc
    float* bgxf = (float*)(wf + OFF_BGX);
    for (int d = tid; d < 512; d += nth) {
        float sc = ((d >> 7) == 2) ? (2.f * L2E) : L2E;
        bgxf[d] = (bih[d] + bhh[d]) * sc;
    }
}

// ---------------- K1: encoder (3 layers) + gate-preact GEMM, full run ----------------
// 512 blocks x 256 thr, 8 chunks/wave. Writes the ENTIRE gx (268 MB fp16) in one
// dispatch; hid3 intermediate is never materialized. High-t chunks first so t=0
// is L3-freshest when the scan starts.
__global__ __launch_bounds__(256, 2) void k1_enc(
    const float* __restrict__ x, const float* __restrict__ b1, const float* __restrict__ b2,
    const float* __restrict__ b3, const u16* __restrict__ wf, u16* __restrict__ gx) {
    __shared__ __align__(16) u16 scr[4][2560];  // per-wave: 2048 (K=128 frag) + 512 (K=32 frag)

    int tid = threadIdx.x, wv = tid >> 6, lane = tid & 63;
    int m = lane & 15, q = lane >> 4;
    u16* s1 = scr[wv];
    u16* s2 = scr[wv] + 2048;
    const short8* W1v = (const short8*)(wf + OFF_W1);
    const short8* W2v = (const short8*)(wf + OFF_W2);
    const short8* W3v = (const short8*)(wf + OFF_W3);
    const short8* WIv = (const short8*)(wf + OFF_WIH);
    const float* bgxf = (const float*)(wf + OFF_BGX);
    // hoist W1, W3 fragments (W2 + Wih stay in-loop: L2-hot across 512 blocks)
    short8 w1r[32], w3r[8];
#pragma unroll
    for (int i = 0; i < 32; ++i) w1r[i] = W1v[i * 64 + lane];
#pragma unroll
    for (int i = 0; i < 8; ++i) w3r[i] = W3v[i * 64 + lane];
    int wid = blockIdx.x * 4 + wv;  // 2048 waves total

    for (int it = 7; it >= 0; --it) {   // reverse: low-t chunks written last (L3-fresh)
        int c = wid + it * 2048;        // chunk: rows [16c, 16c+16); bI = c&63, t = c>>6
        short8 a1[4];
        const float* xr = x + (size_t)(c * 16 + m) * 128 + q * 8;
#pragma unroll
        for (int kc = 0; kc < 4; ++kc) {
            f4 f0 = *(const f4*)(xr + kc * 32);
            f4 f1 = *(const f4*)(xr + kc * 32 + 4);
            a1[kc] = pack8(f0, f1);
        }
        // Layer 1: 128 -> 128
#pragma unroll
        for (int nt = 0; nt < 8; ++nt) {
            f4 acc = {0.f, 0.f, 0.f, 0.f};
#pragma unroll
            for (int kc = 0; kc < 4; ++kc) acc = MFMA(a1[kc], w1r[nt * 4 + kc], acc);
            int col = nt * 16 + m;
            float bb = b1[col];
            int base = (col >> 5) * 512 + ((col >> 3) & 3) * 128 + (col & 7);
#pragma unroll
            for (int p = 0; p < 4; ++p) {
                float v = acc[p] + bb; v = v > 0.f ? v : 0.f;
                s1[base + (q * 4 + p) * 8] = f2bf(v);
            }
        }
        asm volatile("s_waitcnt lgkmcnt(0)" ::: "memory");  // scratch is wave-private
        short8 a2[4];
#pragma unroll
        for (int kc = 0; kc < 4; ++kc) a2[kc] = *(const short8*)(s1 + kc * 512 + lane * 8);
        // Layer 2: 128 -> 32
#pragma unroll
        for (int nt = 0; nt < 2; ++nt) {
            f4 acc = {0.f, 0.f, 0.f, 0.f};
#pragma unroll
            for (int kc = 0; kc < 4; ++kc) acc = MFMA(a2[kc], W2v[(nt * 4 + kc) * 64 + lane], acc);
            int col = nt * 16 + m;
            float bb = b2[col];
            int base = (col >> 3) * 128 + (col & 7);
#pragma unroll
            for (int p = 0; p < 4; ++p) {
                float v = acc[p] + bb; v = v > 0.f ? v : 0.f;
                s2[base + (q * 4 + p) * 8] = f2bf(v);
            }
        }
        asm volatile("s_waitcnt lgkmcnt(0)" ::: "memory");
        short8 a3 = *(const short8*)(s2 + lane * 8);
        // Layer 3: 32 -> 128
#pragma unroll
        for (int nt = 0; nt < 8; ++nt) {
            f4 acc = {0.f, 0.f, 0.f, 0.f};
            acc = MFMA(a3, w3r[nt], acc);
            int col = nt * 16 + m;
            float bb = b3[col];
            int base = (col >> 5) * 512 + ((col >> 3) & 3) * 128 + (col & 7);
#pragma unroll
            for (int p = 0; p < 4; ++p) {
                float v = acc[p] + bb; v = v > 0.f ? v : 0.f;
                s1[base + (q * 4 + p) * 8] = f2bf(v);
            }
        }
        asm volatile("s_waitcnt lgkmcnt(0)" ::: "memory");
        // gate-preact GEMM: gx = hid3 @ Wih^T + (bih+bhh), all pre-scaled, fp16 out
        short8 a4[4];
#pragma unroll
        for (int kc = 0; kc < 4; ++kc) a4[kc] = *(const short8*)(s1 + kc * 512 + lane * 8);
        int bI = c & 63, tt = c >> 6;
        _Float16* gxo = (_Float16*)gx + (size_t)(bI * TT + tt) * 8192;
#pragma unroll 4
        for (int nt = 0; nt < 32; ++nt) {
            f4 acc = {0.f, 0.f, 0.f, 0.f};
#pragma unroll
            for (int kc = 0; kc < 4; ++kc) acc = MFMA(a4[kc], WIv[(nt * 4 + kc) * 64 + lane], acc);
            int col = nt * 16 + m;
            float bb = bgxf[col];
            h4 hv;
#pragma unroll
            for (int p = 0; p < 4; ++p) hv[p] = (_Float16)(acc[p] + bb);
            *(h4*)(gxo + col * 16 + 4 * q) = hv;  // [col][row] fp16, 8B coalesced store
        }
    }
}

// ---------------- K3: LSTM scan + fused heads (64 blocks x 512 thr, 256 steps) ----------------
// With gx precomputed, the scan needs only Whh: 16 fragments = 64 VGPR/wave, OPAQ-
// pinned resident. Total demand ~165 < 256-VGPR cap at 2 waves/SIMD. No per-step
// weight traffic of any kind (register-resident); gx streams with 2-deep prefetch.
__global__ __launch_bounds__(512, 1) void k3_scan(
    const u16* __restrict__ gx, const u16* __restrict__ wf, const float* __restrict__ done,
    const float* __restrict__ h0, const float* __restrict__ c0,
    const float* __restrict__ ba, const float* __restrict__ bc, float* __restrict__ out) {
    __shared__ __align__(16) u16 hbuf[2][2048];  // 16 rows x 128 bf16, frag order, dbl-buffered
    __shared__ __align__(16) float dls[4096];    // (1-done) for 256 t x 16 rows

    int tid = threadIdx.x, wv = tid >> 6, lane = tid & 63;
    int m = lane & 15, q = lane >> 4;
    int bI = blockIdx.x, rb = bI * 16;
    int u = wv * 16 + m;  // this wave's hidden-unit column

    const short8* WHv = (const short8*)(wf + OFF_WHH);
    const short8* WAv = (const short8*)(wf + OFF_WA);
    short8 wh[4][4];  // gate g tile nt = g*8+wv -> 64 VGPR, pinned resident
#pragma unroll
    for (int g = 0; g < 4; ++g)
#pragma unroll
        for (int kc = 0; kc < 4; ++kc)
            wh[g][kc] = WHv[((g * 8 + wv) * 4 + kc) * 64 + lane];
#pragma unroll
    for (int g = 0; g < 4; ++g)
#pragma unroll
        for (int kc = 0; kc < 4; ++kc) OPAQ(wh[g][kc]);

    // head fragments (waves 0,1): unpinned; possible remat = 4 L1-hot loads, negligible
    short8 wab[4];
    float hb = 0.f;
    int hcol = wv * 16 + m;
    if (wv < 2) {
#pragma unroll
        for (int kc = 0; kc < 4; ++kc) wab[kc] = WAv[(wv * 4 + kc) * 64 + lane];
        if (hcol < 18) hb = ba[hcol];
        else if (hcol == 18) hb = bc[0];
    }

    for (int i = tid; i < 4096; i += 512) {
        int t = i >> 4, r = i & 15;
        dls[i] = 1.0f - done[(size_t)t * BB + rb + r];
    }
    float cst[4];
#pragma unroll
    for (int k = 0; k < 4; ++k) {
        int r = 4 * q + k;
        cst[k] = c0[(size_t)(rb + r) * 128 + u];
        float hv = h0[(size_t)(rb + r) * 128 + u];
        hbuf[0][(u >> 5) * 512 + (((u >> 3) & 3) * 16 + r) * 8 + (u & 7)] = f2bf(hv);
    }
    const _Float16* gxf = (const _Float16*)gx + (size_t)bI * (TT * 8192);
    // 2-deep gx prefetch: gA = even steps, gB = odd steps (round-7-verified pattern)
    h4 gA[4], gB[4];
#pragma unroll
    for (int g = 0; g < 4; ++g) {
        gA[g] = *(const h4*)(gxf + (size_t)(g * 128 + u) * 16 + 4 * q);
        gB[g] = *(const h4*)(gxf + 8192 + (size_t)(g * 128 + u) * 16 + 4 * q);
    }
    __syncthreads();

    // step s: consume GU, refill it for s+2 AFTER consumption (round-4-verified)
    auto step = [&](int s, h4 (&GU)[4]) __attribute__((always_inline)) {
        const u16* hc = hbuf[s & 1];
        u16* hn = hbuf[(s + 1) & 1];
        f4 dm = *(const f4*)(dls + s * 16 + 4 * q);
        short8 ah[4];
#pragma unroll
        for (int kc = 0; kc < 4; ++kc) ah[kc] = *(const short8*)(hc + kc * 512 + lane * 8);
        f4 aH[4];
#pragma unroll
        for (int g = 0; g < 4; ++g) aH[g] = (f4){0.f, 0.f, 0.f, 0.f};
#pragma unroll
        for (int kc = 0; kc < 4; ++kc)
#pragma unroll
            for (int g = 0; g < 4; ++g) aH[g] = MFMA(ah[kc], wh[g][kc], aH[g]);
        // fused head for step s-1 (ah holds h_{s-1}); waves 0,1 only
        if (wv < 2 && s > 0) {
            f4 hacc = {0.f, 0.f, 0.f, 0.f};
#pragma unroll
            for (int kc = 0; kc < 4; ++kc) hacc = MFMA(ah[kc], wab[kc], hacc);
            if (hcol < 19) {
                size_t n0 = (size_t)(s - 1) * BB + rb + 4 * q;
#pragma unroll
                for (int p = 0; p < 4; ++p) out[(n0 + p) * 19 + hcol] = hacc[p] + hb;
            }
        }
        // combine preacts (GU dead afterwards -> refill early)
        f4 pre[4];
#pragma unroll
        for (int g = 0; g < 4; ++g)
#pragma unroll
            for (int k = 0; k < 4; ++k) pre[g][k] = (float)GU[g][k] + dm[k] * aH[g][k];
        if (s + 2 < TT) {
#pragma unroll
            for (int g = 0; g < 4; ++g)
                GU[g] = *(const h4*)(gxf + (size_t)(s + 2) * 8192 + (size_t)(g * 128 + u) * 16 + 4 * q);
        }
#pragma unroll
        for (int k = 0; k < 4; ++k) {
            float ii = sig_pre(pre[0][k]), ff = sig_pre(pre[1][k]), oo = sig_pre(pre[3][k]);
            float gg = 2.f * sig_pre(pre[2][k]) - 1.f;   // tanh via pre-scaled sigmoid
            float cc = ff * (dm[k] * cst[k]) + ii * gg;
            cst[k] = cc;
            float hh = oo * tanhf_fast(cc);
            hn[(u >> 5) * 512 + (((u >> 3) & 3) * 16 + (4 * q + k)) * 8 + (u & 7)] = f2bf(hh);
        }
        // barrier needs ONLY the LDS writes drained; gx prefetch + out stores in flight
        asm volatile("s_waitcnt lgkmcnt(0)" ::: "memory");
        __builtin_amdgcn_s_barrier();
        asm volatile("" ::: "memory");
    };

    for (int s = 0; s < TT; s += 2) {
        step(s, gA);
        step(s + 1, gB);
    }
    // final head: t_out = 255, h_255 lives in hbuf[0]
    if (wv < 2) {
        short8 ah[4];
#pragma unroll
        for (int kc = 0; kc < 4; ++kc) ah[kc] = *(const short8*)(hbuf[0] + kc * 512 + lane * 8);
        f4 hacc = {0.f, 0.f, 0.f, 0.f};
#pragma unroll
        for (int kc = 0; kc < 4; ++kc) hacc = MFMA(ah[kc], wab[kc], hacc);
        if (hcol < 19) {
            size_t n0 = (size_t)(TT - 1) * BB + rb + 4 * q;
#pragma unroll
            for (int p = 0; p < 4; ++p) out[(n0 + p) * 19 + hcol] = hacc[p] + hb;
        }
    }
}

extern "C" void kernel_launch(void* const* d_in, const int* in_sizes, int n_in,
                              void* d_out, int out_size, void* d_ws, size_t ws_size,
                              hipStream_t stream) {
    const float* x    = (const float*)d_in[0];
    const float* done = (const float*)d_in[1];
    const float* h0   = (const float*)d_in[2];
    const float* c0   = (const float*)d_in[3];
    const float* W1   = (const float*)d_in[4];
    const float* b1   = (const float*)d_in[5];
    const float* W2   = (const float*)d_in[6];
    const float* b2   = (const float*)d_in[7];
    const float* W3   = (const float*)d_in[8];
    const float* b3   = (const float*)d_in[9];
    const float* Wih  = (const float*)d_in[10];
    const float* Whh  = (const float*)d_in[11];
    const float* bih  = (const float*)d_in[12];
    const float* bhh  = (const float*)d_in[13];
    const float* Wa   = (const float*)d_in[14];
    const float* ba   = (const float*)d_in[15];
    const float* Wc   = (const float*)d_in[16];
    const float* bc   = (const float*)d_in[17];
    float* out = (float*)d_out;

    u16* ws  = (u16*)d_ws;
    u16* gxb = ws + WS_GX;      // 268.4 MB fp16 gate preacts (full run)
    u16* wf  = ws + WS_WF;      // 321 KB converted weights + biases
    // total ws needed: 268,756,992 B (harness memsets 512 MiB => fits)

    hipLaunchKernelGGL(k0_conv, dim3(128), dim3(256), 0, stream,
                       W1, W2, W3, Wih, Whh, Wa, Wc, bih, bhh, wf);
    hipLaunchKernelGGL(k1_enc, dim3(512), dim3(256), 0, stream,
                       x, b1, b2, b3, wf, gxb);
    hipLaunchKernelGGL(k3_scan, dim3(64), dim3(512), 0, stream,
                       gxb, wf, done, h0, c0, ba, bc, out);
}